// Round 1
// baseline (642.862 us; speedup 1.0000x reference)
//
#include <hip/hip_runtime.h>
#include <hip/hip_bf16.h>
#include <math.h>

#define GAMMA 0.05f
#define BM 128
#define BN 128
#define BK 64
#define LDS_STRIDE 132   // 128 + 4 floats: keeps float4 rows 16B-aligned, staggers banks

// ws layout:
//   bytes [0..23]   : 3 doubles  (acc_xx, acc_yy, acc_xy)  -- zeroed each launch
//   bytes [64 ..)   : float normsN[n], then float normsR[m]

__global__ __launch_bounds__(256) void row_norms_kernel(const float* __restrict__ X,
                                                        float* __restrict__ out, int d) {
    // one wave per row, 4 rows per 256-thread block
    int row  = blockIdx.x * 4 + (threadIdx.x >> 6);
    int lane = threadIdx.x & 63;
    const float* p = X + (size_t)row * d;
    float s = 0.f;
    for (int k = lane; k < d; k += 64) { float v = p[k]; s = fmaf(v, v, s); }
    #pragma unroll
    for (int off = 32; off > 0; off >>= 1) s += __shfl_down(s, off);
    if (lane == 0) out[row] = s;
}

// mode 0: A=N,B=N, weight W_i*W_j   (upper-triangle blocks only, off-diag x2)
// mode 1: A=R,B=R, weight 1         (upper-triangle blocks only, off-diag x2)
// mode 2: A=N,B=R, weight W_i       (full grid)
__global__ __launch_bounds__(256, 2) void mmd_tile_kernel(
    const float* __restrict__ Nmat, const float* __restrict__ Rmat,
    const float* __restrict__ W,
    const float* __restrict__ normsN, const float* __restrict__ normsR,
    double* __restrict__ acc, int d)
{
    const int mode = blockIdx.z;
    const int bi = blockIdx.y;
    const int bj = blockIdx.x;

    const float* A; const float* B; const float* nrmA; const float* nrmB;
    if (mode == 0)      { A = Nmat; B = Nmat; nrmA = normsN; nrmB = normsN; }
    else if (mode == 1) { A = Rmat; B = Rmat; nrmA = normsR; nrmB = normsR; }
    else                { A = Nmat; B = Rmat; nrmA = normsN; nrmB = normsR; }

    float scale = 1.0f;
    if (mode < 2) {
        if (bj < bi) return;          // symmetric: skip lower triangle
        if (bj > bi) scale = 2.0f;    // count off-diagonal blocks twice
    }

    __shared__ float As[BK][LDS_STRIDE];
    __shared__ float Bs[BK][LDS_STRIDE];

    const int tid = threadIdx.x;
    const int tr = tid >> 4;    // 0..15
    const int tc = tid & 15;    // 0..15

    float accv[8][8];
    #pragma unroll
    for (int i = 0; i < 8; ++i)
        #pragma unroll
        for (int j = 0; j < 8; ++j) accv[i][j] = 0.f;

    const size_t rowA0 = (size_t)bi * BM;
    const size_t rowB0 = (size_t)bj * BN;

    for (int kc = 0; kc < d; kc += BK) {
        // stage [128 rows][64 k] of A and B, transposed to K-major in LDS
        #pragma unroll
        for (int i = 0; i < 8; ++i) {
            int idx = tid + i * 256;        // 0..2047
            int row = idx >> 4;             // 0..127
            int k4  = (idx & 15) << 2;      // 0,4,...,60
            float4 va = *(const float4*)(A + (rowA0 + row) * d + kc + k4);
            As[k4 + 0][row] = va.x;
            As[k4 + 1][row] = va.y;
            As[k4 + 2][row] = va.z;
            As[k4 + 3][row] = va.w;
            float4 vb = *(const float4*)(B + (rowB0 + row) * d + kc + k4);
            Bs[k4 + 0][row] = vb.x;
            Bs[k4 + 1][row] = vb.y;
            Bs[k4 + 2][row] = vb.z;
            Bs[k4 + 3][row] = vb.w;
        }
        __syncthreads();

        #pragma unroll 4
        for (int k = 0; k < BK; ++k) {
            float4 a0 = *(const float4*)&As[k][tr * 8];
            float4 a1 = *(const float4*)&As[k][tr * 8 + 4];
            float4 b0 = *(const float4*)&Bs[k][tc * 8];
            float4 b1 = *(const float4*)&Bs[k][tc * 8 + 4];
            float a[8] = {a0.x, a0.y, a0.z, a0.w, a1.x, a1.y, a1.z, a1.w};
            float b[8] = {b0.x, b0.y, b0.z, b0.w, b1.x, b1.y, b1.z, b1.w};
            #pragma unroll
            for (int i = 0; i < 8; ++i)
                #pragma unroll
                for (int j = 0; j < 8; ++j)
                    accv[i][j] = fmaf(a[i], b[j], accv[i][j]);
        }
        __syncthreads();
    }

    // epilogue: d2 = ||a||^2 + ||b||^2 - 2 a.b ; K = exp(-gamma*d2); weighted sum
    const int gi0 = (int)rowA0 + tr * 8;
    const int gj0 = (int)rowB0 + tc * 8;
    float na[8], nb[8], wa[8], wb[8];
    #pragma unroll
    for (int i = 0; i < 8; ++i) {
        na[i] = nrmA[gi0 + i];
        nb[i] = nrmB[gj0 + i];
    }
    if (mode == 0) {
        #pragma unroll
        for (int i = 0; i < 8; ++i) { wa[i] = W[gi0 + i]; wb[i] = W[gj0 + i]; }
    } else if (mode == 1) {
        #pragma unroll
        for (int i = 0; i < 8; ++i) { wa[i] = 1.f; wb[i] = 1.f; }
    } else {
        #pragma unroll
        for (int i = 0; i < 8; ++i) { wa[i] = W[gi0 + i]; wb[i] = 1.f; }
    }

    float part = 0.f;
    #pragma unroll
    for (int i = 0; i < 8; ++i) {
        float pr = 0.f;
        #pragma unroll
        for (int j = 0; j < 8; ++j) {
            float d2 = na[i] + nb[j] - 2.f * accv[i][j];
            d2 = fmaxf(d2, 0.f);
            pr = fmaf(wb[j], expf(-GAMMA * d2), pr);
        }
        part = fmaf(wa[i], pr, part);
    }
    part *= scale;

    // block reduction in double, then one atomic per block
    double dp = (double)part;
    #pragma unroll
    for (int off = 32; off > 0; off >>= 1) dp += __shfl_down(dp, off);
    __shared__ double red[4];
    if ((tid & 63) == 0) red[tid >> 6] = dp;
    __syncthreads();
    if (tid == 0) {
        double t = red[0] + red[1] + red[2] + red[3];
        atomicAdd(&acc[mode], t);
    }
}

__global__ __launch_bounds__(256) void finalize_kernel(const float* __restrict__ W,
                                                       const double* __restrict__ acc,
                                                       float* __restrict__ out,
                                                       int n, int m) {
    __shared__ double red[256];
    double s = 0.0;
    for (int i = threadIdx.x; i < n; i += 256) s += (double)W[i];
    red[threadIdx.x] = s;
    __syncthreads();
    for (int stride = 128; stride > 0; stride >>= 1) {
        if (threadIdx.x < stride) red[threadIdx.x] += red[threadIdx.x + stride];
        __syncthreads();
    }
    if (threadIdx.x == 0) {
        double S  = red[0];
        double xx = acc[0] / (S * S);
        double yy = acc[1] / ((double)m * (double)m);
        double xy = acc[2] / (S * (double)m);
        double mmd = xx + yy - 2.0 * xy;
        out[0] = (float)sqrt(fmax(mmd, 0.0));
    }
}

extern "C" void kernel_launch(void* const* d_in, const int* in_sizes, int n_in,
                              void* d_out, int out_size, void* d_ws, size_t ws_size,
                              hipStream_t stream) {
    const float* Nmat = (const float*)d_in[0];
    const float* Rmat = (const float*)d_in[1];
    const float* W    = (const float*)d_in[2];
    float* out = (float*)d_out;

    const int n = in_sizes[2];            // 8192 (weights count)
    const int d = in_sizes[0] / n;        // 128
    const int m = in_sizes[1] / d;        // 8192

    double* acc   = (double*)d_ws;
    float* normsN = (float*)((char*)d_ws + 64);
    float* normsR = normsN + n;

    hipMemsetAsync(d_ws, 0, 64, stream);  // zero the 3 accumulators

    row_norms_kernel<<<n / 4, 256, 0, stream>>>(Nmat, normsN, d);
    row_norms_kernel<<<m / 4, 256, 0, stream>>>(Rmat, normsR, d);

    dim3 grid(m / BN, n / BM, 3);         // n == m == 8192 here
    mmd_tile_kernel<<<grid, 256, 0, stream>>>(Nmat, Rmat, W, normsN, normsR, acc, d);

    finalize_kernel<<<1, 256, 0, stream>>>(W, acc, out, n, m);
}

// Round 2
// 313.896 us; speedup vs baseline: 2.0480x; 2.0480x over previous
//
#include <hip/hip_runtime.h>
#include <hip/hip_bf16.h>
#include <math.h>

#define GAMMA 0.05f

typedef __attribute__((ext_vector_type(8))) short bf16x8;
typedef __attribute__((ext_vector_type(4))) float f32x4;

static __device__ __forceinline__ unsigned f32_to_bf16(float x) {
    unsigned u = __float_as_uint(x);
    u += 0x7fffu + ((u >> 16) & 1u);   // round-to-nearest-even
    return u >> 16;
}
static __device__ __forceinline__ float bf16hi_to_f32(unsigned h) {
    return __uint_as_float(h << 16);
}

// ws layout:
//   bytes [0..23]  : 3 doubles (acc_xx, acc_yy, acc_xy) -- zeroed each launch
//   bytes [64 ..)  : float normsN[n], then float normsR[m]

__global__ __launch_bounds__(256) void row_norms_kernel(const float* __restrict__ X,
                                                        float* __restrict__ out, int d) {
    int row  = blockIdx.x * 4 + (threadIdx.x >> 6);
    int lane = threadIdx.x & 63;
    const float* p = X + (size_t)row * d;
    float s = 0.f;
    for (int k = lane; k < d; k += 64) { float v = p[k]; s = fmaf(v, v, s); }
    #pragma unroll
    for (int off = 32; off > 0; off >>= 1) s += __shfl_down(s, off);
    if (lane == 0) out[row] = s;
}

// One block = 128x128 output tile. d=128 entirely resident in LDS as bf16 hi/lo.
// LDS: Ahi[128][128] | Alo | Bhi | Blo  (32 KB each), rows K-contiguous,
// XOR-swizzled: byte_in_row ^= (row&7)<<4  (conflict-free ds_read_b128 across rows).
// mode 0: A=B=N, w_i*w_j, upper-tri x2 ; mode 1: A=B=R, 1 ; mode 2: A=N,B=R, w_i
__global__ __launch_bounds__(512) void mmd_mfma_kernel(
    const float* __restrict__ Nmat, const float* __restrict__ Rmat,
    const float* __restrict__ W,
    const float* __restrict__ normsN, const float* __restrict__ normsR,
    double* __restrict__ acc3, int d)
{
    const int mode = blockIdx.z;
    const int bi = blockIdx.y, bj = blockIdx.x;

    const float *A, *B, *nrmA, *nrmB;
    if (mode == 0)      { A = Nmat; B = Nmat; nrmA = normsN; nrmB = normsN; }
    else if (mode == 1) { A = Rmat; B = Rmat; nrmA = normsR; nrmB = normsR; }
    else                { A = Nmat; B = Rmat; nrmA = normsN; nrmB = normsR; }

    float scale = 1.0f;
    if (mode < 2) {
        if (bj < bi) return;
        if (bj > bi) scale = 2.0f;
    }

    __shared__ __align__(16) char ldsB[131072 + 64];

    const size_t rowA0 = (size_t)bi * 128;
    const size_t rowB0 = (size_t)bj * 128;
    const int tid = threadIdx.x;

    // ---- stage: f32 -> bf16 hi/lo, K-contiguous swizzled LDS ----
    #pragma unroll
    for (int it = 0; it < 4; ++it) {
        int idx = tid + it * 512;        // 0..2047
        int row = idx >> 4;              // 0..127
        int kg  = (idx & 15) << 3;       // 0,8,...,120
        int dst = row * 256 + ((kg << 1) ^ ((row & 7) << 4));

        const float* pa = A + (rowA0 + row) * d + kg;
        const float* pb = B + (rowB0 + row) * d + kg;
        float af[8], bf_[8];
        *(float4*)(af)     = *(const float4*)(pa);
        *(float4*)(af + 4) = *(const float4*)(pa + 4);
        *(float4*)(bf_)     = *(const float4*)(pb);
        *(float4*)(bf_ + 4) = *(const float4*)(pb + 4);

        unsigned ha[8], la[8], hb[8], lb[8];
        #pragma unroll
        for (int j = 0; j < 8; ++j) {
            ha[j] = f32_to_bf16(af[j]);
            la[j] = f32_to_bf16(af[j] - bf16hi_to_f32(ha[j]));
            hb[j] = f32_to_bf16(bf_[j]);
            lb[j] = f32_to_bf16(bf_[j] - bf16hi_to_f32(hb[j]));
        }
        uint4 v;
        v.x = ha[0] | (ha[1] << 16); v.y = ha[2] | (ha[3] << 16);
        v.z = ha[4] | (ha[5] << 16); v.w = ha[6] | (ha[7] << 16);
        *(uint4*)(ldsB + dst) = v;
        v.x = la[0] | (la[1] << 16); v.y = la[2] | (la[3] << 16);
        v.z = la[4] | (la[5] << 16); v.w = la[6] | (la[7] << 16);
        *(uint4*)(ldsB + 32768 + dst) = v;
        v.x = hb[0] | (hb[1] << 16); v.y = hb[2] | (hb[3] << 16);
        v.z = hb[4] | (hb[5] << 16); v.w = hb[6] | (hb[7] << 16);
        *(uint4*)(ldsB + 65536 + dst) = v;
        v.x = lb[0] | (lb[1] << 16); v.y = lb[2] | (lb[3] << 16);
        v.z = lb[4] | (lb[5] << 16); v.w = lb[6] | (lb[7] << 16);
        *(uint4*)(ldsB + 98304 + dst) = v;
    }
    __syncthreads();

    const int lane = tid & 63;
    const int w  = tid >> 6;        // 0..7
    const int wm = w >> 2;          // 0..1 : row half
    const int wn = w & 3;           // 0..3 : col quarter
    const int lg = lane >> 4;       // 0..3
    const int lr = lane & 15;

    int arow[4], brow[2];
    #pragma unroll
    for (int mi = 0; mi < 4; ++mi) arow[mi] = wm * 64 + mi * 16 + lr;
    #pragma unroll
    for (int nj = 0; nj < 2; ++nj) brow[nj] = wn * 32 + nj * 16 + lr;

    f32x4 acc[4][2];
    #pragma unroll
    for (int mi = 0; mi < 4; ++mi)
        #pragma unroll
        for (int nj = 0; nj < 2; ++nj)
            acc[mi][nj] = (f32x4){0.f, 0.f, 0.f, 0.f};

    // ---- MFMA: C = Ahi*Bhi^T + Ahi*Blo^T + Alo*Bhi^T over K=128 (4 steps of 32) ----
    #pragma unroll
    for (int ks = 0; ks < 4; ++ks) {
        int kb = ks * 64 + lg * 16;   // byte offset of this lane-group's 8 bf16
        bf16x8 ahi[4], alo[4], bhi[2], blo[2];
        #pragma unroll
        for (int mi = 0; mi < 4; ++mi) {
            int off = arow[mi] * 256 + (kb ^ ((arow[mi] & 7) << 4));
            ahi[mi] = *(const bf16x8*)(ldsB + off);
            alo[mi] = *(const bf16x8*)(ldsB + 32768 + off);
        }
        #pragma unroll
        for (int nj = 0; nj < 2; ++nj) {
            int off = brow[nj] * 256 + (kb ^ ((brow[nj] & 7) << 4));
            bhi[nj] = *(const bf16x8*)(ldsB + 65536 + off);
            blo[nj] = *(const bf16x8*)(ldsB + 98304 + off);
        }
        #pragma unroll
        for (int mi = 0; mi < 4; ++mi)
            #pragma unroll
            for (int nj = 0; nj < 2; ++nj) {
                acc[mi][nj] = __builtin_amdgcn_mfma_f32_16x16x32_bf16(ahi[mi], bhi[nj], acc[mi][nj], 0, 0, 0);
                acc[mi][nj] = __builtin_amdgcn_mfma_f32_16x16x32_bf16(ahi[mi], blo[nj], acc[mi][nj], 0, 0, 0);
                acc[mi][nj] = __builtin_amdgcn_mfma_f32_16x16x32_bf16(alo[mi], bhi[nj], acc[mi][nj], 0, 0, 0);
            }
    }

    // ---- epilogue: d2 -> exp -> weighted partial sum ----
    float nb2[2], wb2[2];
    #pragma unroll
    for (int nj = 0; nj < 2; ++nj) {
        int gj = (int)rowB0 + wn * 32 + nj * 16 + lr;
        nb2[nj] = nrmB[gj];
        wb2[nj] = (mode == 0) ? W[gj] : 1.0f;
    }
    float part = 0.f;
    #pragma unroll
    for (int mi = 0; mi < 4; ++mi) {
        #pragma unroll
        for (int r = 0; r < 4; ++r) {
            int gi = (int)rowA0 + wm * 64 + mi * 16 + lg * 4 + r;
            float na = nrmA[gi];
            float wv = (mode == 1) ? 1.0f : W[gi];
            float rowsum = 0.f;
            #pragma unroll
            for (int nj = 0; nj < 2; ++nj) {
                float d2 = fmaxf(na + nb2[nj] - 2.0f * acc[mi][nj][r], 0.0f);
                rowsum = fmaf(wb2[nj], __expf(-GAMMA * d2), rowsum);
            }
            part = fmaf(wv, rowsum, part);
        }
    }
    part *= scale;

    double dp = (double)part;
    #pragma unroll
    for (int off = 32; off > 0; off >>= 1) dp += __shfl_down(dp, off);
    double* red = (double*)(ldsB + 131072);
    if (lane == 0) red[w] = dp;
    __syncthreads();
    if (tid == 0) {
        double t = 0.0;
        #pragma unroll
        for (int i = 0; i < 8; ++i) t += red[i];
        atomicAdd(&acc3[mode], t);
    }
}

__global__ __launch_bounds__(256) void finalize_kernel(const float* __restrict__ W,
                                                       const double* __restrict__ acc,
                                                       float* __restrict__ out,
                                                       int n, int m) {
    __shared__ double red[256];
    double s = 0.0;
    for (int i = threadIdx.x; i < n; i += 256) s += (double)W[i];
    red[threadIdx.x] = s;
    __syncthreads();
    for (int stride = 128; stride > 0; stride >>= 1) {
        if (threadIdx.x < stride) red[threadIdx.x] += red[threadIdx.x + stride];
        __syncthreads();
    }
    if (threadIdx.x == 0) {
        double S  = red[0];
        double xx = acc[0] / (S * S);
        double yy = acc[1] / ((double)m * (double)m);
        double xy = acc[2] / (S * (double)m);
        double mmd = xx + yy - 2.0 * xy;
        out[0] = (float)sqrt(fmax(mmd, 0.0));
    }
}

extern "C" void kernel_launch(void* const* d_in, const int* in_sizes, int n_in,
                              void* d_out, int out_size, void* d_ws, size_t ws_size,
                              hipStream_t stream) {
    const float* Nmat = (const float*)d_in[0];
    const float* Rmat = (const float*)d_in[1];
    const float* W    = (const float*)d_in[2];
    float* out = (float*)d_out;

    const int n = in_sizes[2];            // 8192
    const int d = in_sizes[0] / n;        // 128
    const int m = in_sizes[1] / d;        // 8192

    double* acc   = (double*)d_ws;
    float* normsN = (float*)((char*)d_ws + 64);
    float* normsR = normsN + n;

    hipMemsetAsync(d_ws, 0, 64, stream);

    row_norms_kernel<<<n / 4, 256, 0, stream>>>(Nmat, normsN, d);
    row_norms_kernel<<<m / 4, 256, 0, stream>>>(Rmat, normsR, d);

    dim3 grid(m / 128, n / 128, 3);
    mmd_mfma_kernel<<<grid, 512, 0, stream>>>(Nmat, Rmat, W, normsN, normsR, acc, d);

    finalize_kernel<<<1, 256, 0, stream>>>(W, acc, out, n, m);
}

// Round 3
// 181.616 us; speedup vs baseline: 3.5397x; 1.7283x over previous
//
#include <hip/hip_runtime.h>
#include <hip/hip_bf16.h>
#include <math.h>

#define GAMMA 0.05f

typedef __attribute__((ext_vector_type(8))) short bf16x8;
typedef __attribute__((ext_vector_type(4))) float f32x4;

static __device__ __forceinline__ unsigned f32_to_bf16(float x) {
    unsigned u = __float_as_uint(x);
    u += 0x7fffu + ((u >> 16) & 1u);   // RNE
    return u >> 16;
}

static __device__ __forceinline__ void gload_lds16(const void* g, void* l) {
    __builtin_amdgcn_global_load_lds(
        (const __attribute__((address_space(1))) void*)g,
        (__attribute__((address_space(3))) void*)l, 16, 0, 0);
}

// ws layout (bytes):
//   0      : 3 doubles (acc_xx, acc_yy, acc_xy) -- zeroed each launch
//   1024   : float normsN[8192]   (32 KB)
//   33792  : float normsR[8192]   (32 KB)
//   66560  : bf16 Nsw[8192][128]  (2 MB)  pre-swizzled rows
//   2163712: bf16 Rsw[8192][128]  (2 MB)
// Row swizzle (within each 256-byte row): byte ^= (row&7)<<4  -- makes the
// 16-lane ds_read_b128 column reads in the tile kernel bank-conflict-free.

__global__ __launch_bounds__(256) void prep_kernel(const float* __restrict__ X,
                                                   float* __restrict__ norms,
                                                   unsigned short* __restrict__ Xsw) {
    // one wave per row (d=128), 4 rows per block; fused norm + bf16 convert
    int row  = blockIdx.x * 4 + (threadIdx.x >> 6);
    int lane = threadIdx.x & 63;
    const float* p = X + (size_t)row * 128;
    float2 v = *(const float2*)(p + lane * 2);
    float s = fmaf(v.x, v.x, v.y * v.y);
    unsigned h = f32_to_bf16(v.x) | (f32_to_bf16(v.y) << 16);
    int boff = (lane * 4) ^ ((row & 7) << 4);
    *(unsigned*)((char*)Xsw + (size_t)row * 256 + boff) = h;
    #pragma unroll
    for (int off = 32; off > 0; off >>= 1) s += __shfl_down(s, off);
    if (lane == 0) norms[row] = s;
}

// One block = 128x128 tile. A,B bf16 tiles staged via global_load_lds (linear,
// sources pre-swizzled). Gram via mfma hi*hi only; diagonal fixed to K=1.
// mode 0: A=B=N, w_i*w_j, upper-tri x2 ; mode 1: A=B=R, 1 ; mode 2: A=N,B=R, w_i
__global__ __launch_bounds__(512, 4) void mmd_mfma_kernel(
    const unsigned short* __restrict__ Nsw, const unsigned short* __restrict__ Rsw,
    const float* __restrict__ W,
    const float* __restrict__ normsN, const float* __restrict__ normsR,
    double* __restrict__ acc3)
{
    const int mode = blockIdx.z;
    const int bi = blockIdx.y, bj = blockIdx.x;
    if (mode < 2 && bj < bi) return;

    const unsigned short *A, *B; const float *nrmA, *nrmB;
    if (mode == 0)      { A = Nsw; B = Nsw; nrmA = normsN; nrmB = normsN; }
    else if (mode == 1) { A = Rsw; B = Rsw; nrmA = normsR; nrmB = normsR; }
    else                { A = Nsw; B = Rsw; nrmA = normsN; nrmB = normsR; }

    const float scale = (mode < 2 && bj > bi) ? 2.0f : 1.0f;
    const bool diagblk = (mode < 2 && bi == bj);

    __shared__ __align__(16) char lds[65536];   // A tile 32KB | B tile 32KB
    __shared__ double red[8];

    const int tid  = threadIdx.x;
    const int lane = tid & 63;
    const int wv   = tid >> 6;      // 0..7

    // ---- stage: 64 KB via global_load_lds, fully linear (src pre-swizzled) ----
    const char* gA = (const char*)A + (size_t)bi * 128 * 256;
    const char* gB = (const char*)B + (size_t)bj * 128 * 256;
    #pragma unroll
    for (int it = 0; it < 4; ++it) {
        int loff = (wv * 4 + it) * 1024;        // wave-uniform LDS base
        gload_lds16(gA + loff + lane * 16, lds + loff);
        gload_lds16(gB + loff + lane * 16, lds + 32768 + loff);
    }
    __syncthreads();   // emits s_waitcnt vmcnt(0) + barrier

    const int wm = wv >> 2;         // 0..1 : 64-row half
    const int wn = wv & 3;          // 0..3 : 32-col quarter
    const int lg = lane >> 4;       // 0..3
    const int lr = lane & 15;

    f32x4 acc[4][2];
    #pragma unroll
    for (int mi = 0; mi < 4; ++mi)
        #pragma unroll
        for (int nj = 0; nj < 2; ++nj) acc[mi][nj] = (f32x4){0.f,0.f,0.f,0.f};

    #pragma unroll
    for (int ks = 0; ks < 4; ++ks) {
        int kb = ks * 64 + lg * 16;   // byte offset of this lane-group's 8 bf16
        bf16x8 af[4], bfr[2];
        #pragma unroll
        for (int mi = 0; mi < 4; ++mi) {
            int r = wm * 64 + mi * 16 + lr;
            af[mi] = *(const bf16x8*)(lds + r * 256 + (kb ^ ((r & 7) << 4)));
        }
        #pragma unroll
        for (int nj = 0; nj < 2; ++nj) {
            int r = wn * 32 + nj * 16 + lr;
            bfr[nj] = *(const bf16x8*)(lds + 32768 + r * 256 + (kb ^ ((r & 7) << 4)));
        }
        #pragma unroll
        for (int mi = 0; mi < 4; ++mi)
            #pragma unroll
            for (int nj = 0; nj < 2; ++nj)
                acc[mi][nj] = __builtin_amdgcn_mfma_f32_16x16x32_bf16(af[mi], bfr[nj], acc[mi][nj], 0, 0, 0);
    }

    // ---- epilogue ----
    float nb2[2], wb2[2];
    #pragma unroll
    for (int nj = 0; nj < 2; ++nj) {
        int cj = wn * 32 + nj * 16 + lr;
        int gj = bj * 128 + cj;
        nb2[nj] = nrmB[gj];
        wb2[nj] = (mode == 0) ? W[gj] : 1.0f;
    }
    float part = 0.f;
    #pragma unroll
    for (int mi = 0; mi < 4; ++mi) {
        #pragma unroll
        for (int r = 0; r < 4; ++r) {
            int ci = wm * 64 + mi * 16 + lg * 4 + r;
            int gi = bi * 128 + ci;
            float na = nrmA[gi];
            float wv_ = (mode == 1) ? 1.0f : W[gi];
            float rowsum = 0.f;
            #pragma unroll
            for (int nj = 0; nj < 2; ++nj) {
                int cj = wn * 32 + nj * 16 + lr;
                float d2 = fmaxf(na + nb2[nj] - 2.0f * acc[mi][nj][r], 0.0f);
                float K = __expf(-GAMMA * d2);
                if (diagblk && ci == cj) K = 1.0f;   // exact self-kernel
                rowsum = fmaf(wb2[nj], K, rowsum);
            }
            part = fmaf(wv_, rowsum, part);
        }
    }
    part *= scale;

    double dp = (double)part;
    #pragma unroll
    for (int off = 32; off > 0; off >>= 1) dp += __shfl_down(dp, off);
    if (lane == 0) red[wv] = dp;
    __syncthreads();
    if (tid == 0) {
        double t = 0.0;
        #pragma unroll
        for (int i = 0; i < 8; ++i) t += red[i];
        atomicAdd(&acc3[mode], t);
    }
}

__global__ __launch_bounds__(256) void finalize_kernel(const float* __restrict__ W,
                                                       const double* __restrict__ acc,
                                                       float* __restrict__ out,
                                                       int n, int m) {
    __shared__ double red[256];
    double s = 0.0;
    for (int i = threadIdx.x; i < n; i += 256) s += (double)W[i];
    red[threadIdx.x] = s;
    __syncthreads();
    for (int stride = 128; stride > 0; stride >>= 1) {
        if (threadIdx.x < stride) red[threadIdx.x] += red[threadIdx.x + stride];
        __syncthreads();
    }
    if (threadIdx.x == 0) {
        double S  = red[0];
        double xx = acc[0] / (S * S);
        double yy = acc[1] / ((double)m * (double)m);
        double xy = acc[2] / (S * (double)m);
        double mmd = xx + yy - 2.0 * xy;
        out[0] = (float)sqrt(fmax(mmd, 0.0));
    }
}

extern "C" void kernel_launch(void* const* d_in, const int* in_sizes, int n_in,
                              void* d_out, int out_size, void* d_ws, size_t ws_size,
                              hipStream_t stream) {
    const float* Nmat = (const float*)d_in[0];
    const float* Rmat = (const float*)d_in[1];
    const float* W    = (const float*)d_in[2];
    float* out = (float*)d_out;

    const int n = in_sizes[2];            // 8192
    const int d = in_sizes[0] / n;        // 128
    const int m = in_sizes[1] / d;        // 8192

    double* acc            = (double*)d_ws;
    float* normsN          = (float*)((char*)d_ws + 1024);
    float* normsR          = (float*)((char*)d_ws + 33792);
    unsigned short* Nsw    = (unsigned short*)((char*)d_ws + 66560);
    unsigned short* Rsw    = (unsigned short*)((char*)d_ws + 66560 + 2097152);

    hipMemsetAsync(d_ws, 0, 64, stream);

    prep_kernel<<<n / 4, 256, 0, stream>>>(Nmat, normsN, Nsw);
    prep_kernel<<<m / 4, 256, 0, stream>>>(Rmat, normsR, Rsw);

    dim3 grid(m / 128, n / 128, 3);
    mmd_mfma_kernel<<<grid, 512, 0, stream>>>(Nsw, Rsw, W, normsN, normsR, acc);

    finalize_kernel<<<1, 256, 0, stream>>>(W, acc, out, n, m);
}